// Round 8
// baseline (220.725 us; speedup 1.0000x reference)
//
#include <hip/hip_runtime.h>
#include <math.h>

typedef short bf16x8 __attribute__((ext_vector_type(8)));
typedef float f32x4  __attribute__((ext_vector_type(4)));
typedef unsigned short ushort_t;

#define N_SMPS 16384
#define N_FCNS 2048
#define D_IN 32
#define D_OUT 32
#define KNN 4
#define SPLITS 4
#define CPS 512            // centers per split
#define TILES 32           // CPS / 16
#define NPAIR (N_SMPS * KNN)

__device__ __forceinline__ unsigned umin_u(unsigned a, unsigned b) { return a < b ? a : b; }
__device__ __forceinline__ unsigned umax_u(unsigned a, unsigned b) { return a > b ? a : b; }

// round-to-nearest-even fp32 -> bf16
__device__ __forceinline__ ushort_t bf16_rne(float f) {
  unsigned b = __float_as_uint(f);
  unsigned r = b + 0x7FFFu + ((b >> 16) & 1u);
  return (ushort_t)(r >> 16);
}

// ---------------- ws layout (bytes) ------------------------------------------
#define OFF_XH   0u
#define OFF_XL   (1u << 20)
#define OFF_CH   (2u << 20)
#define OFF_CL   (OFF_CH + 131072u)
#define OFF_HB   (OFF_CL + 131072u)
#define OFF_CAND (OFF_HB + 8192u)
#define OFF_IDX  (OFF_CAND + (SPLITS * N_SMPS * 32u))   // +2 MB
#define OFF_CNT  (OFF_IDX + (NPAIR * 4u))               // +256 KB
#define OFF_CNT2 (OFF_CNT + 8192u)
#define OFF_BASE (OFF_CNT2 + 8192u)                     // 2049 ints, pad to 8448
#define OFF_LIST (OFF_BASE + 8448u)                     // 65536 ints = 256 KB
#define OFF_PART (OFF_LIST + (NPAIR * 4u))              // 8 MB
// total ~10.8 MB

// ---------------- Kernel 0: bf16 hi/lo split (RNE) + center half-norms -------
__global__ __launch_bounds__(256) void k_prep(
    const float* __restrict__ x, const float* __restrict__ ctrs,
    ushort_t* __restrict__ xh, ushort_t* __restrict__ xl,
    ushort_t* __restrict__ ch, ushort_t* __restrict__ cl,
    float* __restrict__ hb)
{
  const int gt = blockIdx.x * 256 + threadIdx.x;
  const int NX4 = N_SMPS * D_IN / 4;   // 131072
  const int NC4 = N_FCNS * D_IN / 4;   // 16384

  const float* src; ushort_t* dh; ushort_t* dl; int i4;
  if (gt < NX4) { src = x; dh = xh; dl = xl; i4 = gt; }
  else          { src = ctrs; dh = ch; dl = cl; i4 = gt - NX4; }
  if (gt < NX4 + NC4) {
    float4 v = ((const float4*)src)[i4];
    float vv[4] = {v.x, v.y, v.z, v.w};
    ushort_t h[4], l[4];
    #pragma unroll
    for (int q = 0; q < 4; ++q) {
      ushort_t hh = bf16_rne(vv[q]);
      float hf = __uint_as_float(((unsigned)hh) << 16);
      h[q] = hh;
      l[q] = bf16_rne(vv[q] - hf);
    }
    ushort_t* ph = dh + 4 * i4; ushort_t* pl = dl + 4 * i4;
    #pragma unroll
    for (int q = 0; q < 4; ++q) { ph[q] = h[q]; pl[q] = l[q]; }
  }
  if (gt < N_FCNS) {
    const float4* cp4 = (const float4*)(ctrs + (size_t)gt * D_IN);
    float a = 0.f;
    #pragma unroll
    for (int q = 0; q < 8; ++q) {
      float4 v = cp4[q];
      a += v.x * v.x + v.y * v.y + v.z * v.z + v.w * v.w;
    }
    hb[gt] = -0.5f * a;
  }
}

// ---------------- Kernel 1: MFMA scores + packed-key top-6 per split ---------
// (unchanged -- proven)
__global__ __launch_bounds__(256, 4) void k_topk(
    const ushort_t* __restrict__ xh, const ushort_t* __restrict__ xl,
    const ushort_t* __restrict__ ch, const ushort_t* __restrict__ cl,
    const float* __restrict__ hb, unsigned* __restrict__ cand)
{
  __shared__ unsigned s_mrg[4][16 * 68];

  const int tid = threadIdx.x;
  const int lane = tid & 63;
  const int w = __builtin_amdgcn_readfirstlane(tid >> 6);
  const int col = lane & 15;
  const int quad = lane >> 4;
  const int sbase = blockIdx.x * 16;
  const int nbase0 = w * CPS;

  const bf16x8 ah = *(const bf16x8*)(xh + (size_t)(sbase + col) * D_IN + quad * 8);
  const bf16x8 al = *(const bf16x8*)(xl + (size_t)(sbase + col) * D_IN + quad * 8);

  unsigned ls[4][4];
  #pragma unroll
  for (int r = 0; r < 4; ++r)
    #pragma unroll
    for (int e = 0; e < 4; ++e) ls[r][e] = 0u;

  #pragma unroll 2
  for (int t = 0; t < TILES; ++t) {
    const int nb = nbase0 + t * 16;
    const bf16x8 bh = *(const bf16x8*)(ch + (size_t)(nb + col) * D_IN + quad * 8);
    const bf16x8 bl = *(const bf16x8*)(cl + (size_t)(nb + col) * D_IN + quad * 8);
    const float hbv = hb[nb + col];
    f32x4 acc = {0.f, 0.f, 0.f, 0.f};
    acc = __builtin_amdgcn_mfma_f32_16x16x32_bf16(ah, bh, acc, 0, 0, 0);
    acc = __builtin_amdgcn_mfma_f32_16x16x32_bf16(ah, bl, acc, 0, 0, 0);
    acc = __builtin_amdgcn_mfma_f32_16x16x32_bf16(al, bh, acc, 0, 0, 0);
    acc = __builtin_amdgcn_mfma_f32_16x16x32_bf16(al, bl, acc, 0, 0, 0);
    const unsigned tc = (unsigned)(t * 16 + col);
    #pragma unroll
    for (int r = 0; r < 4; ++r) {
      const float u = acc[r] + hbv;
      unsigned b = __float_as_uint(u);
      unsigned m = b ^ ((unsigned)((int)b >> 31) | 0x80000000u);
      unsigned key = (m & 0xFFFFFE00u) | tc;
      unsigned t0 = umin_u(ls[r][0], key); ls[r][0] = umax_u(ls[r][0], key);
      unsigned t1 = umin_u(ls[r][1], t0);  ls[r][1] = umax_u(ls[r][1], t0);
      unsigned t2 = umin_u(ls[r][2], t1);  ls[r][2] = umax_u(ls[r][2], t1);
      ls[r][3] = umax_u(ls[r][3], t2);
    }
  }

  unsigned* mrg = s_mrg[w];
  #pragma unroll
  for (int r = 0; r < 4; ++r) {
    const int row = quad * 4 + r;
    *(uint4*)(mrg + row * 68 + col * 4) =
        make_uint4(ls[r][0], ls[r][1], ls[r][2], ls[r][3]);
  }
  __syncthreads();

  if (lane < 16) {
    unsigned q0 = 0, q1 = 0, q2 = 0, q3 = 0, q4 = 0, q5 = 0;
    const uint4* rp = (const uint4*)(mrg + lane * 68);
    #pragma unroll
    for (int c2 = 0; c2 < 16; ++c2) {
      uint4 kv = rp[c2];
      unsigned ks[4] = {kv.x, kv.y, kv.z, kv.w};
      #pragma unroll
      for (int e = 0; e < 4; ++e) {
        unsigned key = ks[e];
        unsigned t0 = umin_u(q0, key); q0 = umax_u(q0, key);
        unsigned t1 = umin_u(q1, t0);  q1 = umax_u(q1, t0);
        unsigned t2 = umin_u(q2, t1);  q2 = umax_u(q2, t1);
        unsigned t3 = umin_u(q3, t2);  q3 = umax_u(q3, t2);
        unsigned t4 = umin_u(q4, t3);  q4 = umax_u(q4, t3);
        q5 = umax_u(q5, t4);
      }
    }
    unsigned* op = cand + ((size_t)w * N_SMPS + sbase + lane) * 8;
    *(uint4*)op = make_uint4(q0, q1, q2, q3);
    *(uint2*)(op + 4) = make_uint2(q4, q5);
  }
}

// ---------------- Kernel 1b: fp64-exact top-4 + bucket counting --------------
#define KM_BLOCK 128

__global__ __launch_bounds__(KM_BLOCK) void k_merge(
    const float* __restrict__ x, const float* __restrict__ ctrs,
    const unsigned* __restrict__ cand, int* __restrict__ idx_out,
    int* __restrict__ cnt)
{
  const int s = blockIdx.x * KM_BLOCK + threadIdx.x;

  int nn[SPLITS * 6];
  #pragma unroll
  for (int sp = 0; sp < SPLITS; ++sp) {
    const unsigned* ip = cand + ((size_t)sp * N_SMPS + s) * 8;
    uint4 a = *(const uint4*)ip;
    uint2 b = *(const uint2*)(ip + 4);
    nn[sp * 6 + 0] = sp * CPS + (int)(a.x & 0x1FFu);
    nn[sp * 6 + 1] = sp * CPS + (int)(a.y & 0x1FFu);
    nn[sp * 6 + 2] = sp * CPS + (int)(a.z & 0x1FFu);
    nn[sp * 6 + 3] = sp * CPS + (int)(a.w & 0x1FFu);
    nn[sp * 6 + 4] = sp * CPS + (int)(b.x & 0x1FFu);
    nn[sp * 6 + 5] = sp * CPS + (int)(b.y & 0x1FFu);
  }

  double xd[D_IN];
  {
    const float4* xp = (const float4*)(x + (size_t)s * D_IN);
    #pragma unroll
    for (int q = 0; q < 8; ++q) {
      float4 v = xp[q];
      xd[4 * q + 0] = (double)v.x; xd[4 * q + 1] = (double)v.y;
      xd[4 * q + 2] = (double)v.z; xd[4 * q + 3] = (double)v.w;
    }
  }

  double bd[4]; int b4[4];
  #pragma unroll
  for (int e = 0; e < 4; ++e) { bd[e] = 1e300; b4[e] = 0x7fffffff; }
  for (int m = 0; m < SPLITS * 6; ++m) {
    const int j = nn[m];
    const float* cp = ctrs + (size_t)j * D_IN;
    double d2a = 0.0, d2b = 0.0;
    #pragma unroll
    for (int d = 0; d < D_IN; d += 2) {
      double df0 = xd[d] - (double)cp[d];
      double df1 = xd[d + 1] - (double)cp[d + 1];
      d2a = fma(df0, df0, d2a);
      d2b = fma(df1, df1, d2b);
    }
    double d2 = d2a + d2b;
    bool ins = (d2 < bd[3]) || (d2 == bd[3] && j < b4[3]);
    if (ins) {
      bd[3] = d2; b4[3] = j;
      #pragma unroll
      for (int q = 3; q > 0; --q) {
        bool sw = (bd[q] < bd[q - 1]) || (bd[q] == bd[q - 1] && b4[q] < b4[q - 1]);
        if (sw) {
          double td = bd[q]; bd[q] = bd[q - 1]; bd[q - 1] = td;
          int    tj = b4[q]; b4[q] = b4[q - 1]; b4[q - 1] = tj;
        }
      }
    }
  }
  #pragma unroll
  for (int q = 0; q < 4; ++q) {
    idx_out[s * KNN + q] = b4[q];
    atomicAdd(&cnt[b4[q]], 1);           // bucket histogram (value-determ.)
  }
}

// ---------------- Kernel 1c: exclusive prefix over 2048 counts ---------------
__global__ __launch_bounds__(256) void k_scan(
    const int* __restrict__ cnt, int* __restrict__ base)
{
  __shared__ int s_sum[256];
  const int tid = threadIdx.x;
  int loc[8]; int acc = 0;
  #pragma unroll
  for (int q = 0; q < 8; ++q) { loc[q] = acc; acc += cnt[tid * 8 + q]; }
  s_sum[tid] = acc;
  __syncthreads();
  #pragma unroll
  for (int off = 1; off < 256; off <<= 1) {
    int v = (tid >= off) ? s_sum[tid - off] : 0;
    __syncthreads();
    s_sum[tid] += v;
    __syncthreads();
  }
  const int pre = (tid == 0) ? 0 : s_sum[tid - 1];
  #pragma unroll
  for (int q = 0; q < 8; ++q) base[tid * 8 + q] = pre + loc[q];
  if (tid == 255) base[N_FCNS] = pre + acc;   // = NPAIR
}

// ---------------- Kernel 2a: place pairs into dense compacted list -----------
__global__ __launch_bounds__(256) void k_place(
    const int* __restrict__ idx, const int* __restrict__ base,
    int* __restrict__ cnt2, int* __restrict__ list)
{
  const int t = blockIdx.x * 256 + threadIdx.x;   // t = s*4 + j
  const int f = idx[t];
  const int pos = base[f] + atomicAdd(&cnt2[f], 1);
  list[pos] = t;                                   // every pair placed: no cap
}

// ---------------- Kernel 2b: center-major apply ------------------------------
// Block = center f. W_f (4 KB) staged in LDS once; chunks of 8 samples x 32
// output cols. Partials indexed by unique (s,j) -> deterministic values.
__global__ __launch_bounds__(256) void k_apply_inv(
    const float* __restrict__ x, const float* __restrict__ ctrs,
    const float* __restrict__ wts, const float* __restrict__ offs,
    const int* __restrict__ base, const int* __restrict__ list,
    float* __restrict__ part)
{
  __shared__ float s_w[D_IN * D_OUT];      // [d][c] row-major
  __shared__ float s_diff[8][D_IN + 1];

  const int f = blockIdx.x;
  const int tid = threadIdx.x;
  const int si = tid >> 5;                 // 0..7 sample slot
  const int c = tid & 31;                  // output col / dim

  {
    const float4* wg = (const float4*)(wts + (size_t)f * (D_IN * D_OUT));
    ((float4*)s_w)[tid] = wg[tid];
  }
  const float creg = ctrs[(size_t)f * D_IN + c];
  const float offc = offs[(size_t)f * D_OUT + c];
  const int start = base[f];
  const int n = base[f + 1] - start;
  __syncthreads();

  for (int i0 = 0; i0 < n; i0 += 8) {
    const int i = i0 + si;
    int sv = -1;
    if (i < n) sv = list[start + i];
    if (sv >= 0) {
      const int s = sv >> 2;
      s_diff[si][c] = x[(size_t)s * D_IN + c] - creg;
    }
    __syncthreads();
    if (sv >= 0) {
      float a0 = offc, a1 = 0.f, a2 = 0.f, a3 = 0.f;
      #pragma unroll
      for (int d = 0; d < D_IN; d += 4) {
        a0 = fmaf(s_diff[si][d + 0], s_w[(d + 0) * D_OUT + c], a0);
        a1 = fmaf(s_diff[si][d + 1], s_w[(d + 1) * D_OUT + c], a1);
        a2 = fmaf(s_diff[si][d + 2], s_w[(d + 2) * D_OUT + c], a2);
        a3 = fmaf(s_diff[si][d + 3], s_w[(d + 3) * D_OUT + c], a3);
      }
      part[(size_t)sv * D_OUT + c] = (a0 + a1) + (a2 + a3);
    }
    __syncthreads();
  }
}

// ---------------- Kernel 2c: reduce 4 partials per sample --------------------
__global__ __launch_bounds__(256) void k_reduce(
    const float* __restrict__ part, float* __restrict__ y)
{
  const int t = blockIdx.x * 256 + threadIdx.x;   // t = s*8 + c4
  const int s = t >> 3;
  const int c4 = t & 7;
  const float4* p = (const float4*)(part + (size_t)s * 4 * D_OUT) + c4;
  float4 a = p[0], b = p[8], c = p[16], e = p[24];
  float4 o;
  o.x = (a.x + b.x) + (c.x + e.x);
  o.y = (a.y + b.y) + (c.y + e.y);
  o.z = (a.z + b.z) + (c.z + e.z);
  o.w = (a.w + b.w) + (c.w + e.w);
  ((float4*)(y + (size_t)s * D_OUT))[c4] = o;
}

// ---------------- launch -----------------------------------------------------
extern "C" void kernel_launch(void* const* d_in, const int* in_sizes, int n_in,
                              void* d_out, int out_size, void* d_ws, size_t ws_size,
                              hipStream_t stream) {
  const float* x    = (const float*)d_in[0];
  const float* ctrs = (const float*)d_in[1];
  const float* wts  = (const float*)d_in[2];
  const float* offs = (const float*)d_in[3];
  float* y = (float*)d_out;

  char* ws = (char*)d_ws;
  ushort_t* xh = (ushort_t*)(ws + OFF_XH);
  ushort_t* xl = (ushort_t*)(ws + OFF_XL);
  ushort_t* ch = (ushort_t*)(ws + OFF_CH);
  ushort_t* cl = (ushort_t*)(ws + OFF_CL);
  float*    hb = (float*)(ws + OFF_HB);
  unsigned* cand = (unsigned*)(ws + OFF_CAND);
  int*    idxb = (int*)(ws + OFF_IDX);
  int*    cnt  = (int*)(ws + OFF_CNT);
  int*    cnt2 = (int*)(ws + OFF_CNT2);
  int*    base = (int*)(ws + OFF_BASE);
  int*    list = (int*)(ws + OFF_LIST);
  float*  part = (float*)(ws + OFF_PART);

  hipMemsetAsync(cnt, 0, 16384, stream);   // cnt + cnt2 (adjacent)
  k_prep<<<(N_SMPS * D_IN / 4 + N_FCNS * D_IN / 4) / 256, 256, 0, stream>>>(
      x, ctrs, xh, xl, ch, cl, hb);
  k_topk<<<N_SMPS / 16, 256, 0, stream>>>(xh, xl, ch, cl, hb, cand);
  k_merge<<<N_SMPS / KM_BLOCK, KM_BLOCK, 0, stream>>>(x, ctrs, cand, idxb, cnt);
  k_scan<<<1, 256, 0, stream>>>(cnt, base);
  k_place<<<NPAIR / 256, 256, 0, stream>>>(idxb, base, cnt2, list);
  k_apply_inv<<<N_FCNS, 256, 0, stream>>>(x, ctrs, wts, offs, base, list, part);
  k_reduce<<<(N_SMPS * 8) / 256, 256, 0, stream>>>(part, y);
}

// Round 9
// 161.065 us; speedup vs baseline: 1.3704x; 1.3704x over previous
//
#include <hip/hip_runtime.h>
#include <math.h>

typedef short bf16x8 __attribute__((ext_vector_type(8)));
typedef float f32x4  __attribute__((ext_vector_type(4)));

#define N_SMPS 16384
#define N_FCNS 2048
#define D_IN 32
#define D_OUT 32
#define KNN 4
#define SPLITS 4
#define CPS 512            // centers per split (one wave per split)
#define TILES 32           // CPS / 16
#define POOL 48            // 8 subsets x top-6 -> fp64-exact re-rank

__device__ __forceinline__ unsigned umin_u(unsigned a, unsigned b) { return a < b ? a : b; }
__device__ __forceinline__ unsigned umax_u(unsigned a, unsigned b) { return a > b ? a : b; }

// round-to-nearest-even fp32 -> bf16
__device__ __forceinline__ unsigned short bf16_rne(float f) {
  unsigned b = __float_as_uint(f);
  unsigned r = b + 0x7FFFu + ((b >> 16) & 1u);
  return (unsigned short)(r >> 16);
}

// ---------------- Kernel 1: fused knn (convert + MFMA topk + fp64 merge) -----
// Block = 256 thr = 4 waves. Wave w scores this block's 16 samples against
// split w (512 centers, 32 16-col tiles) with ONE bf16 MFMA per tile
// (RNE-converted inline from fp32; ||c||^2 via 8 FMA + 2 shfl_xor over the
// 4 quad-lanes holding the same row). Per-(row,col) top-4 packed keys ->
// LDS -> 8 threads/sample take top-6 of disjoint 32-key subsets -> 48-pool
// -> proven fp64-exact top-4 with np tie-break. One dispatch, no scratch.
__global__ __launch_bounds__(256, 4) void k_knn(
    const float* __restrict__ x, const float* __restrict__ ctrs,
    int* __restrict__ idx_out)
{
  __shared__ unsigned s_cand[SPLITS][16][16][4];   // 16 KB [wave][row][col][e]
  __shared__ double   s_d2[16][POOL];              // 6 KB
  __shared__ int      s_ix[16][POOL];              // 3 KB

  const int tid = threadIdx.x;
  const int lane = tid & 63;
  const int w = __builtin_amdgcn_readfirstlane(tid >> 6);  // wave = split
  const int col = lane & 15;
  const int quad = lane >> 4;
  const int sbase = blockIdx.x * 16;
  const int nbase0 = w * CPS;

  // A-frag: x[sbase+col][quad*8 .. +8) fp32 -> bf16 RNE (16 B/lane, coalesced)
  bf16x8 ah;
  {
    const float4* xp =
        (const float4*)(x + (size_t)(sbase + col) * D_IN + quad * 8);
    float4 v0 = xp[0], v1 = xp[1];
    float xf[8] = {v0.x, v0.y, v0.z, v0.w, v1.x, v1.y, v1.z, v1.w};
    #pragma unroll
    for (int i = 0; i < 8; ++i) ah[i] = (short)bf16_rne(xf[i]);
  }

  unsigned ls[4][4];
  #pragma unroll
  for (int r = 0; r < 4; ++r)
    #pragma unroll
    for (int e = 0; e < 4; ++e) ls[r][e] = 0u;   // real keys always > 0

  #pragma unroll 2
  for (int t = 0; t < TILES; ++t) {
    const int row = nbase0 + t * 16 + col;
    const float4* cp = (const float4*)(ctrs + (size_t)row * D_IN + quad * 8);
    float4 c0 = cp[0], c1 = cp[1];
    float cf[8] = {c0.x, c0.y, c0.z, c0.w, c1.x, c1.y, c1.z, c1.w};
    bf16x8 bh;
    #pragma unroll
    for (int i = 0; i < 8; ++i) bh[i] = (short)bf16_rne(cf[i]);
    // ||c||^2: this lane's quarter + butterfly over the 4 quads of this col
    float pn = 0.f;
    #pragma unroll
    for (int i = 0; i < 8; ++i) pn = fmaf(cf[i], cf[i], pn);
    pn += __shfl_xor(pn, 16, 64);
    pn += __shfl_xor(pn, 32, 64);
    const float hbv = -0.5f * pn;

    f32x4 acc = {0.f, 0.f, 0.f, 0.f};
    acc = __builtin_amdgcn_mfma_f32_16x16x32_bf16(ah, bh, acc, 0, 0, 0);

    const unsigned tc = (unsigned)(t * 16 + col);   // 9-bit local center id
    #pragma unroll
    for (int r = 0; r < 4; ++r) {
      const float u = acc[r] + hbv;                 // score (maximize)
      unsigned b = __float_as_uint(u);
      unsigned m = b ^ ((unsigned)((int)b >> 31) | 0x80000000u);  // monotone
      unsigned key = (m & 0xFFFFFE00u) | tc;
      unsigned t0 = umin_u(ls[r][0], key); ls[r][0] = umax_u(ls[r][0], key);
      unsigned t1 = umin_u(ls[r][1], t0);  ls[r][1] = umax_u(ls[r][1], t0);
      unsigned t2 = umin_u(ls[r][2], t1);  ls[r][2] = umax_u(ls[r][2], t1);
      ls[r][3] = umax_u(ls[r][3], t2);
    }
  }

  // stage per-(row,col) top-4 keys (uint4/lane: 2-way bank alias only)
  #pragma unroll
  for (int r = 0; r < 4; ++r) {
    const int row = quad * 4 + r;
    *(uint4*)&s_cand[w][row][col][0] =
        make_uint4(ls[r][0], ls[r][1], ls[r][2], ls[r][3]);
  }
  __syncthreads();

  // subset top-6 + fp64 distances: thread t<128: sample t>>3, subset t&7
  if (tid < 128) {
    const int sl = tid >> 3;        // local sample 0..15
    const int g  = tid & 7;         // subset: wave g>>1, col-half g&1
    const int wv = g >> 1;
    const int ch = (g & 1) * 8;
    unsigned q0 = 0, q1 = 0, q2 = 0, q3 = 0, q4 = 0, q5 = 0;
    #pragma unroll
    for (int c2 = 0; c2 < 8; ++c2) {
      uint4 kv = *(const uint4*)&s_cand[wv][sl][ch + c2][0];
      unsigned ks[4] = {kv.x, kv.y, kv.z, kv.w};
      #pragma unroll
      for (int e = 0; e < 4; ++e) {
        unsigned key = ks[e];
        unsigned t0 = umin_u(q0, key); q0 = umax_u(q0, key);
        unsigned t1 = umin_u(q1, t0);  q1 = umax_u(q1, t0);
        unsigned t2 = umin_u(q2, t1);  q2 = umax_u(q2, t1);
        unsigned t3 = umin_u(q3, t2);  q3 = umax_u(q3, t2);
        unsigned t4 = umin_u(q4, t3);  q4 = umax_u(q4, t3);
        q5 = umax_u(q5, t4);
      }
    }
    unsigned sel[6] = {q0, q1, q2, q3, q4, q5};
    const float4* xp4 = (const float4*)(x + (size_t)(sbase + sl) * D_IN);
    #pragma unroll
    for (int i = 0; i < 6; ++i) {
      const int j = wv * CPS + (int)(sel[i] & 0x1FFu);
      const float4* cp4 = (const float4*)(ctrs + (size_t)j * D_IN);
      double d2a = 0.0, d2b = 0.0;
      #pragma unroll
      for (int q = 0; q < 8; ++q) {
        float4 cv = cp4[q];
        float4 xv = xp4[q];
        double df0 = (double)xv.x - (double)cv.x;
        double df1 = (double)xv.y - (double)cv.y;
        double df2 = (double)xv.z - (double)cv.z;
        double df3 = (double)xv.w - (double)cv.w;
        d2a = fma(df0, df0, d2a);
        d2b = fma(df1, df1, d2b);
        d2a = fma(df2, df2, d2a);
        d2b = fma(df3, df3, d2b);
      }
      s_d2[sl][g * 6 + i] = d2a + d2b;
      s_ix[sl][g * 6 + i] = j;
    }
  }
  __syncthreads();

  // final: one thread per sample, proven fp64 top-4 with np tie-break
  if (tid < 16) {
    double bd[4]; int b4[4];
    #pragma unroll
    for (int e = 0; e < 4; ++e) { bd[e] = 1e300; b4[e] = 0x7fffffff; }
    for (int m = 0; m < POOL; ++m) {
      const double d2 = s_d2[tid][m];
      const int j = s_ix[tid][m];
      bool ins = (d2 < bd[3]) || (d2 == bd[3] && j < b4[3]);
      if (ins) {
        bd[3] = d2; b4[3] = j;
        #pragma unroll
        for (int q = 3; q > 0; --q) {
          bool sw = (bd[q] < bd[q - 1]) ||
                    (bd[q] == bd[q - 1] && b4[q] < b4[q - 1]);
          if (sw) {
            double td = bd[q]; bd[q] = bd[q - 1]; bd[q - 1] = td;
            int    tj = b4[q]; b4[q] = b4[q - 1]; b4[q - 1] = tj;
          }
        }
      }
    }
    #pragma unroll
    for (int q = 0; q < 4; ++q) idx_out[(sbase + tid) * KNN + q] = b4[q];
  }
}

// ---------------- Kernel 2: gather + apply local affine models ---------------
// (byte-identical to R6's proven k_apply)
#define K2_BLOCK 256
#define K2_SAMPLES 8

__global__ __launch_bounds__(K2_BLOCK) void k_apply(
    const float* __restrict__ x, const float* __restrict__ ctrs,
    const float* __restrict__ wts, const float* __restrict__ offs,
    const int* __restrict__ idx, float* __restrict__ y)
{
  __shared__ float  s_diff[K2_SAMPLES][KNN][D_IN + 1];
  __shared__ float4 s_part[K2_SAMPLES][KNN][D_OUT / 4];
  const int tid = threadIdx.x;
  const int sbase = blockIdx.x * K2_SAMPLES;

  #pragma unroll
  for (int r = 0; r < K2_SAMPLES * KNN * D_IN / K2_BLOCK; ++r) {
    int v = r * K2_BLOCK + tid;
    int d = v & 31; int p = v >> 5;
    int sl = p >> 2; int j = p & 3;
    int f = idx[(sbase + sl) * KNN + j];
    s_diff[sl][j][d] =
        x[(size_t)(sbase + sl) * D_IN + d] - ctrs[(size_t)f * D_IN + d];
  }
  __syncthreads();

  const int sl = tid >> 5;
  const int j  = (tid >> 3) & 3;
  const int eq = tid & 7;
  const int s = sbase + sl;

  const int f = idx[s * KNN + j];
  const float4* wp = (const float4*)(wts + (size_t)f * (D_IN * D_OUT));
  float4 acc = ((const float4*)(offs + (size_t)f * D_OUT))[eq];
  #pragma unroll
  for (int d = 0; d < D_IN; ++d) {
    float4 wv = wp[d * (D_OUT / 4) + eq];
    float xc = s_diff[sl][j][d];
    acc.x = fmaf(xc, wv.x, acc.x);
    acc.y = fmaf(xc, wv.y, acc.y);
    acc.z = fmaf(xc, wv.z, acc.z);
    acc.w = fmaf(xc, wv.w, acc.w);
  }
  s_part[sl][j][eq] = acc;
  __syncthreads();

  if (j == 0) {
    float4 a = s_part[sl][0][eq], b = s_part[sl][1][eq];
    float4 c = s_part[sl][2][eq], e = s_part[sl][3][eq];
    float4 o;
    o.x = (a.x + b.x) + (c.x + e.x);
    o.y = (a.y + b.y) + (c.y + e.y);
    o.z = (a.z + b.z) + (c.z + e.z);
    o.w = (a.w + b.w) + (c.w + e.w);
    ((float4*)(y + (size_t)s * D_OUT))[eq] = o;
  }
}

// ---------------- launch: 2 dispatches ---------------------------------------
extern "C" void kernel_launch(void* const* d_in, const int* in_sizes, int n_in,
                              void* d_out, int out_size, void* d_ws, size_t ws_size,
                              hipStream_t stream) {
  const float* x    = (const float*)d_in[0];
  const float* ctrs = (const float*)d_in[1];
  const float* wts  = (const float*)d_in[2];
  const float* offs = (const float*)d_in[3];
  float* y = (float*)d_out;
  int* idxb = (int*)d_ws;   // 256 KB scratch

  k_knn<<<N_SMPS / 16, 256, 0, stream>>>(x, ctrs, idxb);
  k_apply<<<N_SMPS / K2_SAMPLES, K2_BLOCK, 0, stream>>>(x, ctrs, wts, offs,
                                                        idxb, y);
}

// Round 10
// 143.111 us; speedup vs baseline: 1.5423x; 1.1255x over previous
//
#include <hip/hip_runtime.h>
#include <math.h>

typedef short bf16x8 __attribute__((ext_vector_type(8)));
typedef float f32x4  __attribute__((ext_vector_type(4)));

#define N_SMPS 16384
#define N_FCNS 2048
#define D_IN 32
#define D_OUT 32
#define KNN 4
#define SPLITS 4
#define CPS 512            // centers per split (one wave per split)
#define TILES 32           // CPS / 16
#define POOL 48            // 8 subsets x top-6 -> fp64-exact re-rank

__device__ __forceinline__ unsigned umin_u(unsigned a, unsigned b) { return a < b ? a : b; }
__device__ __forceinline__ unsigned umax_u(unsigned a, unsigned b) { return a > b ? a : b; }

// round-to-nearest-even fp32 -> bf16
__device__ __forceinline__ unsigned short bf16_rne(float f) {
  unsigned b = __float_as_uint(f);
  unsigned r = b + 0x7FFFu + ((b >> 16) & 1u);
  return (unsigned short)(r >> 16);
}

// ---------------- ws layout (bytes) ------------------------------------------
// xh 1MB | ch 128K | hb 8K | wb 4MB | idx 256K  -> ~5.4 MB
#define OFF_XH  0u
#define OFF_CH  1048576u
#define OFF_HB  (OFF_CH + 131072u)
#define OFF_WB  (OFF_HB + 8192u)
#define OFF_IDX (OFF_WB + 4194304u)

#define NX4 (N_SMPS * D_IN / 4)            // 131072
#define NC4 (N_FCNS * D_IN / 4)            // 16384
#define NW4 (N_FCNS * D_IN * D_OUT / 4)    // 524288
#define NTOT (NX4 + NC4 + NW4)             // 671744 = 2624 * 256

// ---------------- Kernel 0: bf16 RNE conversion (x, ctrs, W) + norms ---------
__global__ __launch_bounds__(256) void k_prep(
    const float* __restrict__ x, const float* __restrict__ ctrs,
    const float* __restrict__ wts,
    unsigned short* __restrict__ xh, unsigned short* __restrict__ ch,
    unsigned short* __restrict__ wb, float* __restrict__ hb)
{
  const int gt = blockIdx.x * 256 + threadIdx.x;
  const float* src; unsigned short* dst; int i4;
  if (gt < NX4)            { src = x;    dst = xh; i4 = gt; }
  else if (gt < NX4 + NC4) { src = ctrs; dst = ch; i4 = gt - NX4; }
  else                     { src = wts;  dst = wb; i4 = gt - (NX4 + NC4); }
  float4 v = ((const float4*)src)[i4];
  ushort4 o;
  o.x = bf16_rne(v.x); o.y = bf16_rne(v.y);
  o.z = bf16_rne(v.z); o.w = bf16_rne(v.w);
  ((ushort4*)dst)[i4] = o;

  if (gt < N_FCNS) {   // fp32-exact half-norms from original ctrs
    const float4* cp4 = (const float4*)(ctrs + (size_t)gt * D_IN);
    float a = 0.f;
    #pragma unroll
    for (int q = 0; q < 8; ++q) {
      float4 c = cp4[q];
      a += c.x * c.x + c.y * c.y + c.z * c.z + c.w * c.w;
    }
    hb[gt] = -0.5f * a;
  }
}

// ---------------- Kernel 1: MFMA topk + in-block fp64 merge ------------------
// Block = 256 thr = 4 waves; wave w scores 16 samples vs split w (512 ctrs,
// 32 16-col tiles): 1 bf16 MFMA/tile on PRE-CONVERTED data (no in-loop
// conversion -> no spill, no shfl). Per-(row,col) top-4 packed keys -> LDS ->
// 8 threads/sample top-6 of disjoint 32-key subsets -> 48-pool -> proven
// fp64-exact top-4 with np tie-break. (Selection network identical to R9's
// passing version -> identical indices.)
__global__ __launch_bounds__(256, 4) void k_knn(
    const unsigned short* __restrict__ xh, const unsigned short* __restrict__ ch,
    const float* __restrict__ hb,
    const float* __restrict__ x, const float* __restrict__ ctrs,
    int* __restrict__ idx_out)
{
  __shared__ unsigned s_cand[SPLITS][16][16][4];   // 16 KB
  __shared__ double   s_d2[16][POOL];              // 6 KB
  __shared__ int      s_ix[16][POOL];              // 3 KB

  const int tid = threadIdx.x;
  const int lane = tid & 63;
  const int w = __builtin_amdgcn_readfirstlane(tid >> 6);  // wave = split
  const int col = lane & 15;
  const int quad = lane >> 4;
  const int sbase = blockIdx.x * 16;
  const int nbase0 = w * CPS;

  // A-frag: lane holds A[m=col][k=quad*8+j], 16 B contiguous
  const bf16x8 ah =
      *(const bf16x8*)(xh + (size_t)(sbase + col) * D_IN + quad * 8);

  unsigned ls[4][4];
  #pragma unroll
  for (int r = 0; r < 4; ++r)
    #pragma unroll
    for (int e = 0; e < 4; ++e) ls[r][e] = 0u;   // real keys always > 0

  #pragma unroll 2
  for (int t = 0; t < TILES; ++t) {
    const int nb = nbase0 + t * 16;
    const bf16x8 bh =
        *(const bf16x8*)(ch + (size_t)(nb + col) * D_IN + quad * 8);
    const float hbv = hb[nb + col];
    f32x4 acc = {0.f, 0.f, 0.f, 0.f};
    acc = __builtin_amdgcn_mfma_f32_16x16x32_bf16(ah, bh, acc, 0, 0, 0);
    const unsigned tc = (unsigned)(t * 16 + col);   // 9-bit local center id
    #pragma unroll
    for (int r = 0; r < 4; ++r) {
      const float u = acc[r] + hbv;                 // score (maximize)
      unsigned b = __float_as_uint(u);
      unsigned m = b ^ ((unsigned)((int)b >> 31) | 0x80000000u);  // monotone
      unsigned key = (m & 0xFFFFFE00u) | tc;
      unsigned t0 = umin_u(ls[r][0], key); ls[r][0] = umax_u(ls[r][0], key);
      unsigned t1 = umin_u(ls[r][1], t0);  ls[r][1] = umax_u(ls[r][1], t0);
      unsigned t2 = umin_u(ls[r][2], t1);  ls[r][2] = umax_u(ls[r][2], t1);
      ls[r][3] = umax_u(ls[r][3], t2);
    }
  }

  #pragma unroll
  for (int r = 0; r < 4; ++r) {
    const int row = quad * 4 + r;
    *(uint4*)&s_cand[w][row][col][0] =
        make_uint4(ls[r][0], ls[r][1], ls[r][2], ls[r][3]);
  }
  __syncthreads();

  // subset top-6 + fp64 distances: thread t<128: sample t>>3, subset t&7
  if (tid < 128) {
    const int sl = tid >> 3;        // local sample 0..15
    const int g  = tid & 7;         // subset: wave g>>1, col-half g&1
    const int wv = g >> 1;
    const int chh = (g & 1) * 8;
    unsigned q0 = 0, q1 = 0, q2 = 0, q3 = 0, q4 = 0, q5 = 0;
    #pragma unroll
    for (int c2 = 0; c2 < 8; ++c2) {
      uint4 kv = *(const uint4*)&s_cand[wv][sl][chh + c2][0];
      unsigned ks[4] = {kv.x, kv.y, kv.z, kv.w};
      #pragma unroll
      for (int e = 0; e < 4; ++e) {
        unsigned key = ks[e];
        unsigned t0 = umin_u(q0, key); q0 = umax_u(q0, key);
        unsigned t1 = umin_u(q1, t0);  q1 = umax_u(q1, t0);
        unsigned t2 = umin_u(q2, t1);  q2 = umax_u(q2, t1);
        unsigned t3 = umin_u(q3, t2);  q3 = umax_u(q3, t2);
        unsigned t4 = umin_u(q4, t3);  q4 = umax_u(q4, t3);
        q5 = umax_u(q5, t4);
      }
    }
    unsigned sel[6] = {q0, q1, q2, q3, q4, q5};
    const float4* xp4 = (const float4*)(x + (size_t)(sbase + sl) * D_IN);
    #pragma unroll
    for (int i = 0; i < 6; ++i) {
      const int j = wv * CPS + (int)(sel[i] & 0x1FFu);
      const float4* cp4 = (const float4*)(ctrs + (size_t)j * D_IN);
      double d2a = 0.0, d2b = 0.0;
      #pragma unroll
      for (int q = 0; q < 8; ++q) {
        float4 cv = cp4[q];
        float4 xv = xp4[q];
        double df0 = (double)xv.x - (double)cv.x;
        double df1 = (double)xv.y - (double)cv.y;
        double df2 = (double)xv.z - (double)cv.z;
        double df3 = (double)xv.w - (double)cv.w;
        d2a = fma(df0, df0, d2a);
        d2b = fma(df1, df1, d2b);
        d2a = fma(df2, df2, d2a);
        d2b = fma(df3, df3, d2b);
      }
      s_d2[sl][g * 6 + i] = d2a + d2b;
      s_ix[sl][g * 6 + i] = j;
    }
  }
  __syncthreads();

  // final: one thread per sample, proven fp64 top-4 with np tie-break
  if (tid < 16) {
    double bd[4]; int b4[4];
    #pragma unroll
    for (int e = 0; e < 4; ++e) { bd[e] = 1e300; b4[e] = 0x7fffffff; }
    for (int m = 0; m < POOL; ++m) {
      const double d2 = s_d2[tid][m];
      const int j = s_ix[tid][m];
      bool ins = (d2 < bd[3]) || (d2 == bd[3] && j < b4[3]);
      if (ins) {
        bd[3] = d2; b4[3] = j;
        #pragma unroll
        for (int q = 3; q > 0; --q) {
          bool sw = (bd[q] < bd[q - 1]) ||
                    (bd[q] == bd[q - 1] && b4[q] < b4[q - 1]);
          if (sw) {
            double td = bd[q]; bd[q] = bd[q - 1]; bd[q - 1] = td;
            int    tj = b4[q]; b4[q] = b4[q - 1]; b4[q - 1] = tj;
          }
        }
      }
    }
    #pragma unroll
    for (int q = 0; q < 4; ++q) idx_out[(sbase + tid) * KNN + q] = b4[q];
  }
}

// ---------------- Kernel 2: gather + apply (bf16 W: half the gather bytes) ---
#define K2_BLOCK 256
#define K2_SAMPLES 8

__global__ __launch_bounds__(K2_BLOCK) void k_apply(
    const float* __restrict__ x, const float* __restrict__ ctrs,
    const unsigned short* __restrict__ wb, const float* __restrict__ offs,
    const int* __restrict__ idx, float* __restrict__ y)
{
  __shared__ float  s_diff[K2_SAMPLES][KNN][D_IN + 1];
  __shared__ float4 s_part[K2_SAMPLES][KNN][D_OUT / 4];
  const int tid = threadIdx.x;
  const int sbase = blockIdx.x * K2_SAMPLES;

  #pragma unroll
  for (int r = 0; r < K2_SAMPLES * KNN * D_IN / K2_BLOCK; ++r) {
    int v = r * K2_BLOCK + tid;
    int d = v & 31; int p = v >> 5;
    int sl = p >> 2; int j = p & 3;
    int f = idx[(sbase + sl) * KNN + j];
    s_diff[sl][j][d] =
        x[(size_t)(sbase + sl) * D_IN + d] - ctrs[(size_t)f * D_IN + d];
  }
  __syncthreads();

  const int sl = tid >> 5;
  const int j  = (tid >> 3) & 3;
  const int eq = tid & 7;
  const int s = sbase + sl;

  const int f = idx[s * KNN + j];
  const uint2* wp = (const uint2*)(wb + (size_t)f * (D_IN * D_OUT));
  float4 acc = ((const float4*)(offs + (size_t)f * D_OUT))[eq];
  #pragma unroll
  for (int d = 0; d < D_IN; ++d) {
    uint2 wv = wp[d * 8 + eq];          // 4 bf16 cols
    float w0 = __uint_as_float(wv.x << 16);
    float w1 = __uint_as_float(wv.x & 0xFFFF0000u);
    float w2 = __uint_as_float(wv.y << 16);
    float w3 = __uint_as_float(wv.y & 0xFFFF0000u);
    float xc = s_diff[sl][j][d];
    acc.x = fmaf(xc, w0, acc.x);
    acc.y = fmaf(xc, w1, acc.y);
    acc.z = fmaf(xc, w2, acc.z);
    acc.w = fmaf(xc, w3, acc.w);
  }
  s_part[sl][j][eq] = acc;
  __syncthreads();

  if (j == 0) {
    float4 a = s_part[sl][0][eq], b = s_part[sl][1][eq];
    float4 c = s_part[sl][2][eq], e = s_part[sl][3][eq];
    float4 o;
    o.x = (a.x + b.x) + (c.x + e.x);
    o.y = (a.y + b.y) + (c.y + e.y);
    o.z = (a.z + b.z) + (c.z + e.z);
    o.w = (a.w + b.w) + (c.w + e.w);
    ((float4*)(y + (size_t)s * D_OUT))[eq] = o;
  }
}

// ---------------- launch: 3 dispatches ---------------------------------------
extern "C" void kernel_launch(void* const* d_in, const int* in_sizes, int n_in,
                              void* d_out, int out_size, void* d_ws, size_t ws_size,
                              hipStream_t stream) {
  const float* x    = (const float*)d_in[0];
  const float* ctrs = (const float*)d_in[1];
  const float* wts  = (const float*)d_in[2];
  const float* offs = (const float*)d_in[3];
  float* y = (float*)d_out;

  char* ws = (char*)d_ws;
  unsigned short* xh = (unsigned short*)(ws + OFF_XH);
  unsigned short* ch = (unsigned short*)(ws + OFF_CH);
  float*          hb = (float*)(ws + OFF_HB);
  unsigned short* wb = (unsigned short*)(ws + OFF_WB);
  int*          idxb = (int*)(ws + OFF_IDX);

  k_prep<<<NTOT / 256, 256, 0, stream>>>(x, ctrs, wts, xh, ch, wb, hb);
  k_knn<<<N_SMPS / 16, 256, 0, stream>>>(xh, ch, hb, x, ctrs, idxb);
  k_apply<<<N_SMPS / K2_SAMPLES, K2_BLOCK, 0, stream>>>(x, ctrs, wb, offs,
                                                        idxb, y);
}

// Round 11
// 116.379 us; speedup vs baseline: 1.8966x; 1.2297x over previous
//
#include <hip/hip_runtime.h>
#include <math.h>

typedef short bf16x8 __attribute__((ext_vector_type(8)));
typedef float f32x4  __attribute__((ext_vector_type(4)));

#define N_SMPS 16384
#define N_FCNS 2048
#define D_IN 32
#define D_OUT 32
#define KNN 4
#define SPLITS 4
#define CPS 512            // centers per split (one wave per split)
#define TILES 32           // CPS / 16
#define POOL 48            // 8 subsets x top-6, all-distinct candidates

__device__ __forceinline__ unsigned umin_u(unsigned a, unsigned b) { return a < b ? a : b; }
__device__ __forceinline__ unsigned umax_u(unsigned a, unsigned b) { return a > b ? a : b; }

// round-to-nearest-even fp32 -> bf16
__device__ __forceinline__ unsigned short bf16_rne(float f) {
  unsigned b = __float_as_uint(f);
  unsigned r = b + 0x7FFFu + ((b >> 16) & 1u);
  return (unsigned short)(r >> 16);
}

// ---------------- ws layout (bytes) ------------------------------------------
// xh 1MB | ch 128K | hb 8K | wb 4MB | pool 3MB  -> ~8.2 MB
#define OFF_XH   0u
#define OFF_CH   1048576u
#define OFF_HB   (OFF_CH + 131072u)
#define OFF_WB   (OFF_HB + 8192u)
#define OFF_POOL (OFF_WB + 4194304u)

#define NX4 (N_SMPS * D_IN / 4)            // 131072
#define NC4 (N_FCNS * D_IN / 4)            // 16384
#define NW4 (N_FCNS * D_IN * D_OUT / 4)    // 524288
#define NTOT (NX4 + NC4 + NW4)             // 671744 = 2624 * 256

// ---------------- Kernel 0: bf16 RNE conversion (x, ctrs, W) + norms ---------
__global__ __launch_bounds__(256) void k_prep(
    const float* __restrict__ x, const float* __restrict__ ctrs,
    const float* __restrict__ wts,
    unsigned short* __restrict__ xh, unsigned short* __restrict__ ch,
    unsigned short* __restrict__ wb, float* __restrict__ hb)
{
  const int gt = blockIdx.x * 256 + threadIdx.x;
  const float* src; unsigned short* dst; int i4;
  if (gt < NX4)            { src = x;    dst = xh; i4 = gt; }
  else if (gt < NX4 + NC4) { src = ctrs; dst = ch; i4 = gt - NX4; }
  else                     { src = wts;  dst = wb; i4 = gt - (NX4 + NC4); }
  float4 v = ((const float4*)src)[i4];
  ushort4 o;
  o.x = bf16_rne(v.x); o.y = bf16_rne(v.y);
  o.z = bf16_rne(v.z); o.w = bf16_rne(v.w);
  ((ushort4*)dst)[i4] = o;

  if (gt < N_FCNS) {   // fp32-exact half-norms from original ctrs
    const float4* cp4 = (const float4*)(ctrs + (size_t)gt * D_IN);
    float a = 0.f;
    #pragma unroll
    for (int q = 0; q < 8; ++q) {
      float4 c = cp4[q];
      a += c.x * c.x + c.y * c.y + c.z * c.z + c.w * c.w;
    }
    hb[gt] = -0.5f * a;
  }
}

// ---------------- Kernel 1: MFMA topk -> 48-key pool (NO fp64 tail) ----------
// Block = 256 thr = 4 waves; wave w scores 16 samples vs split w (512 ctrs,
// 32 16-col tiles): 1 bf16 MFMA/tile on pre-converted data. Per-(row,col)
// top-4 packed keys -> LDS -> 8 threads/sample top-6 of disjoint 32-key
// subsets -> pool. fp64 refine deliberately NOT here (register budget).
__global__ __launch_bounds__(256) void k_topk(
    const unsigned short* __restrict__ xh, const unsigned short* __restrict__ ch,
    const float* __restrict__ hb, unsigned* __restrict__ pool)
{
  __shared__ unsigned s_cand[SPLITS][16][16][4];   // 16 KB

  const int tid = threadIdx.x;
  const int lane = tid & 63;
  const int w = __builtin_amdgcn_readfirstlane(tid >> 6);  // wave = split
  const int col = lane & 15;
  const int quad = lane >> 4;
  const int sbase = blockIdx.x * 16;
  const int nbase0 = w * CPS;

  // A-frag: lane holds A[m=col][k=quad*8+j], 16 B contiguous
  const bf16x8 ah =
      *(const bf16x8*)(xh + (size_t)(sbase + col) * D_IN + quad * 8);

  unsigned ls[4][4];
  #pragma unroll
  for (int r = 0; r < 4; ++r)
    #pragma unroll
    for (int e = 0; e < 4; ++e) ls[r][e] = 0u;   // real keys always > 0

  #pragma unroll 2
  for (int t = 0; t < TILES; ++t) {
    const int nb = nbase0 + t * 16;
    const bf16x8 bh =
        *(const bf16x8*)(ch + (size_t)(nb + col) * D_IN + quad * 8);
    const float hbv = hb[nb + col];
    f32x4 acc = {0.f, 0.f, 0.f, 0.f};
    acc = __builtin_amdgcn_mfma_f32_16x16x32_bf16(ah, bh, acc, 0, 0, 0);
    const unsigned tc = (unsigned)(t * 16 + col);   // 9-bit local center id
    #pragma unroll
    for (int r = 0; r < 4; ++r) {
      const float u = acc[r] + hbv;                 // score (maximize)
      unsigned b = __float_as_uint(u);
      unsigned m = b ^ ((unsigned)((int)b >> 31) | 0x80000000u);  // monotone
      unsigned key = (m & 0xFFFFFE00u) | tc;
      unsigned t0 = umin_u(ls[r][0], key); ls[r][0] = umax_u(ls[r][0], key);
      unsigned t1 = umin_u(ls[r][1], t0);  ls[r][1] = umax_u(ls[r][1], t0);
      unsigned t2 = umin_u(ls[r][2], t1);  ls[r][2] = umax_u(ls[r][2], t1);
      ls[r][3] = umax_u(ls[r][3], t2);
    }
  }

  #pragma unroll
  for (int r = 0; r < 4; ++r) {
    const int row = quad * 4 + r;
    *(uint4*)&s_cand[w][row][col][0] =
        make_uint4(ls[r][0], ls[r][1], ls[r][2], ls[r][3]);
  }
  __syncthreads();

  // subset top-6: thread t<128: sample t>>3, subset t&7 (wave g>>1, half g&1)
  if (tid < 128) {
    const int sl = tid >> 3;
    const int g  = tid & 7;
    const int wv = g >> 1;
    const int chh = (g & 1) * 8;
    unsigned q0 = 0, q1 = 0, q2 = 0, q3 = 0, q4 = 0, q5 = 0;
    #pragma unroll
    for (int c2 = 0; c2 < 8; ++c2) {
      uint4 kv = *(const uint4*)&s_cand[wv][sl][chh + c2][0];
      unsigned ks[4] = {kv.x, kv.y, kv.z, kv.w};
      #pragma unroll
      for (int e = 0; e < 4; ++e) {
        unsigned key = ks[e];
        unsigned t0 = umin_u(q0, key); q0 = umax_u(q0, key);
        unsigned t1 = umin_u(q1, t0);  q1 = umax_u(q1, t0);
        unsigned t2 = umin_u(q2, t1);  q2 = umax_u(q2, t1);
        unsigned t3 = umin_u(q3, t2);  q3 = umax_u(q3, t2);
        unsigned t4 = umin_u(q4, t3);  q4 = umax_u(q4, t3);
        q5 = umax_u(q5, t4);
      }
    }
    unsigned* op = pool + (size_t)(sbase + sl) * POOL + g * 6;
    op[0] = q0; op[1] = q1; op[2] = q2;
    op[3] = q3; op[4] = q4; op[5] = q5;
  }
}

// ---------------- Kernel 2: fp64 refine + gather-apply (bf16 W) --------------
// Prologue re-ranks each sample's 48-candidate pool with exact fp64 distances
// (selection identical to R10's passing kernel), then the proven gather/apply.
#define K2_BLOCK 256
#define K2_SAMPLES 8

__global__ __launch_bounds__(K2_BLOCK) void k_apply(
    const float* __restrict__ x, const float* __restrict__ ctrs,
    const unsigned short* __restrict__ wb, const float* __restrict__ offs,
    const unsigned* __restrict__ pool, float* __restrict__ y)
{
  __shared__ double s_pd2[K2_SAMPLES][POOL];          // 3 KB
  __shared__ int    s_pix[K2_SAMPLES][POOL];          // 1.5 KB
  __shared__ int    s_sel[K2_SAMPLES][KNN];
  __shared__ float  s_diff[K2_SAMPLES][KNN][D_IN + 1];
  __shared__ float4 s_part[K2_SAMPLES][KNN][D_OUT / 4];

  const int tid = threadIdx.x;
  const int sbase = blockIdx.x * K2_SAMPLES;

  // --- refine phase 0: exact fp64 distance for each of 8*48 pool entries ---
  for (int c = tid; c < K2_SAMPLES * POOL; c += K2_BLOCK) {
    const int sl = c / POOL;
    const int p = c - sl * POOL;
    const unsigned key = pool[(size_t)(sbase + sl) * POOL + p];
    const int wv = p / 12;                     // subset g=p/6, wave g>>1
    const int j = wv * CPS + (int)(key & 0x1FFu);
    const float4* xp4 = (const float4*)(x + (size_t)(sbase + sl) * D_IN);
    const float4* cp4 = (const float4*)(ctrs + (size_t)j * D_IN);
    double d2a = 0.0, d2b = 0.0;
    #pragma unroll
    for (int q = 0; q < 8; ++q) {
      float4 cv = cp4[q];
      float4 xv = xp4[q];
      double df0 = (double)xv.x - (double)cv.x;
      double df1 = (double)xv.y - (double)cv.y;
      double df2 = (double)xv.z - (double)cv.z;
      double df3 = (double)xv.w - (double)cv.w;
      d2a = fma(df0, df0, d2a);
      d2b = fma(df1, df1, d2b);
      d2a = fma(df2, df2, d2a);
      d2b = fma(df3, df3, d2b);
    }
    s_pd2[sl][p] = d2a + d2b;
    s_pix[sl][p] = j;
  }
  __syncthreads();

  // --- refine phase 1: proven fp64 top-4 with np tie-break (1 thr/sample) ---
  if (tid < K2_SAMPLES) {
    double bd[4]; int b4[4];
    #pragma unroll
    for (int e = 0; e < 4; ++e) { bd[e] = 1e300; b4[e] = 0x7fffffff; }
    for (int m = 0; m < POOL; ++m) {
      const double d2 = s_pd2[tid][m];
      const int j = s_pix[tid][m];
      bool ins = (d2 < bd[3]) || (d2 == bd[3] && j < b4[3]);
      if (ins) {
        bd[3] = d2; b4[3] = j;
        #pragma unroll
        for (int q = 3; q > 0; --q) {
          bool sw = (bd[q] < bd[q - 1]) ||
                    (bd[q] == bd[q - 1] && b4[q] < b4[q - 1]);
          if (sw) {
            double td = bd[q]; bd[q] = bd[q - 1]; bd[q - 1] = td;
            int    tj = b4[q]; b4[q] = b4[q - 1]; b4[q - 1] = tj;
          }
        }
      }
    }
    #pragma unroll
    for (int q = 0; q < 4; ++q) s_sel[tid][q] = b4[q];
  }
  __syncthreads();

  // --- apply: stage (x - c_j), gather bf16 W, accumulate ---
  #pragma unroll
  for (int r = 0; r < K2_SAMPLES * KNN * D_IN / K2_BLOCK; ++r) {
    int v = r * K2_BLOCK + tid;
    int d = v & 31; int p = v >> 5;
    int sl = p >> 2; int j = p & 3;
    int f = s_sel[sl][j];
    s_diff[sl][j][d] =
        x[(size_t)(sbase + sl) * D_IN + d] - ctrs[(size_t)f * D_IN + d];
  }
  __syncthreads();

  const int sl = tid >> 5;
  const int j  = (tid >> 3) & 3;
  const int eq = tid & 7;
  const int s = sbase + sl;

  const int f = s_sel[sl][j];
  const uint2* wp = (const uint2*)(wb + (size_t)f * (D_IN * D_OUT));
  float4 acc = ((const float4*)(offs + (size_t)f * D_OUT))[eq];
  #pragma unroll
  for (int d = 0; d < D_IN; ++d) {
    uint2 wv = wp[d * 8 + eq];          // 4 bf16 cols
    float w0 = __uint_as_float(wv.x << 16);
    float w1 = __uint_as_float(wv.x & 0xFFFF0000u);
    float w2 = __uint_as_float(wv.y << 16);
    float w3 = __uint_as_float(wv.y & 0xFFFF0000u);
    float xc = s_diff[sl][j][d];
    acc.x = fmaf(xc, w0, acc.x);
    acc.y = fmaf(xc, w1, acc.y);
    acc.z = fmaf(xc, w2, acc.z);
    acc.w = fmaf(xc, w3, acc.w);
  }
  s_part[sl][j][eq] = acc;
  __syncthreads();

  if (j == 0) {
    float4 a = s_part[sl][0][eq], b = s_part[sl][1][eq];
    float4 c = s_part[sl][2][eq], e = s_part[sl][3][eq];
    float4 o;
    o.x = (a.x + b.x) + (c.x + e.x);
    o.y = (a.y + b.y) + (c.y + e.y);
    o.z = (a.z + b.z) + (c.z + e.z);
    o.w = (a.w + b.w) + (c.w + e.w);
    ((float4*)(y + (size_t)s * D_OUT))[eq] = o;
  }
}

// ---------------- launch: 3 dispatches ---------------------------------------
extern "C" void kernel_launch(void* const* d_in, const int* in_sizes, int n_in,
                              void* d_out, int out_size, void* d_ws, size_t ws_size,
                              hipStream_t stream) {
  const float* x    = (const float*)d_in[0];
  const float* ctrs = (const float*)d_in[1];
  const float* wts  = (const float*)d_in[2];
  const float* offs = (const float*)d_in[3];
  float* y = (float*)d_out;

  char* ws = (char*)d_ws;
  unsigned short* xh = (unsigned short*)(ws + OFF_XH);
  unsigned short* ch = (unsigned short*)(ws + OFF_CH);
  float*          hb = (float*)(ws + OFF_HB);
  unsigned short* wb = (unsigned short*)(ws + OFF_WB);
  unsigned*     pool = (unsigned*)(ws + OFF_POOL);

  k_prep<<<NTOT / 256, 256, 0, stream>>>(x, ctrs, wts, xh, ch, wb, hb);
  k_topk<<<N_SMPS / 16, 256, 0, stream>>>(xh, ch, hb, pool);
  k_apply<<<N_SMPS / K2_SAMPLES, K2_BLOCK, 0, stream>>>(x, ctrs, wb, offs,
                                                        pool, y);
}